// Round 2
// baseline (174.740 us; speedup 1.0000x reference)
//
#include <hip/hip_runtime.h>
#include <math.h>

typedef _Float16 half_t;
typedef _Float16 half8  __attribute__((ext_vector_type(8)));
typedef _Float16 half4v __attribute__((ext_vector_type(4)));
typedef float    floatx4 __attribute__((ext_vector_type(4)));

#define LOG2E 1.44269504088896f

static __device__ __forceinline__ floatx4 mfma16(half8 a, half8 b, floatx4 c) {
    return __builtin_amdgcn_mfma_f32_16x16x32_f16(a, b, c, 0, 0, 0);
}
static __device__ __forceinline__ floatx4 mfma16x16(half4v a, half4v b, floatx4 c) {
    return __builtin_amdgcn_mfma_f32_16x16x16f16(a, b, c, 0, 0, 0);
}

// ---------------------------------------------------------------------------
// prep (256 thr): z=0 cache_k -> Kc[bh][j][d] fp16 + out_k shift fp32
//                 z=1 cache_v -> Vc4[bh][j/4][d][4] fp16 + out_v shift fp32
//                 z=2 weight transposes + embc build. All float4 loads.
// Vc4 is j-chunked so flash's PV B-frag reads (lane: V^T[d][4 contig j]) are
// coalesced straight from global/L2 -- no LDS staging in flash.
// ---------------------------------------------------------------------------
__global__ __launch_bounds__(256) void prep(const float* __restrict__ cache_k,
                                            const float* __restrict__ cache_v,
                                            const float* __restrict__ Wq,
                                            const float* __restrict__ Wk,
                                            const float* __restrict__ Wv,
                                            const float* __restrict__ Wo,
                                            const float* __restrict__ emb_t,
                                            const float* __restrict__ emb_f,
                                            half_t* __restrict__ Kc,
                                            half_t* __restrict__ Vc4,
                                            float* __restrict__ out_k,
                                            float* __restrict__ out_v,
                                            half_t* __restrict__ WqT,
                                            half_t* __restrict__ WkvT,
                                            half_t* __restrict__ WoT,
                                            half_t* __restrict__ embc)
{
    const int tid = threadIdx.x;
    const int z = blockIdx.z;
    __shared__ float t[64][65];
    if (z == 0) {
        const int bh = blockIdx.y, j0 = blockIdx.x * 64;
        const bool shift = (j0 >= 512);
        #pragma unroll
        for (int i2 = 0; i2 < 4; i2++) {
            int idx = i2 * 256 + tid;
            int d = idx >> 4, j4 = (idx & 15) * 4;
            float4 vv = *(const float4*)&cache_k[((size_t)bh * 64 + d) * 1536 + j0 + j4];
            *(float4*)&t[d][j4] = vv;
            if (shift) *(float4*)&out_k[((size_t)bh * 64 + d) * 1536 + j0 - 512 + j4] = vv;
        }
        __syncthreads();
        #pragma unroll
        for (int i2 = 0; i2 < 2; i2++) {
            int idx = i2 * 256 + tid;
            int j = idx >> 3, db = (idx & 7) * 8;
            half8 o;
            #pragma unroll
            for (int u = 0; u < 8; u++) o[u] = (half_t)t[db + u][j];
            *(half8*)&Kc[((size_t)bh * 1536 + j0 + j) * 64 + db] = o;
        }
    } else if (z == 1) {
        const int bh = blockIdx.y, j0 = blockIdx.x * 64;
        const bool shift = (j0 >= 512);
        #pragma unroll
        for (int i2 = 0; i2 < 4; i2++) {
            int idx = i2 * 256 + tid;
            int j = idx >> 4, d4 = (idx & 15) * 4;
            float4 vv = *(const float4*)&cache_v[((size_t)bh * 1536 + j0 + j) * 64 + d4];
            *(float4*)&t[j][d4] = vv;
            if (shift) *(float4*)&out_v[((size_t)bh * 1536 + j0 + j - 512) * 64 + d4] = vv;
        }
        __syncthreads();
        // Vc4[bh][jc][d][4]: half4 per (jc,d), d fastest over threads (coalesced)
        #pragma unroll
        for (int i2 = 0; i2 < 4; i2++) {
            int idx = i2 * 256 + tid;            // 0..1023
            int jc = idx >> 6, d = idx & 63;     // jc 0..15 local
            half4v o;
            #pragma unroll
            for (int u = 0; u < 4; u++) o[u] = (half_t)t[jc * 4 + u][d];
            *(half4v*)&Vc4[(((size_t)bh * 384 + (j0 >> 2) + jc) * 64 + d) * 4] = o;
        }
    } else {
        const int id = blockIdx.y * 24 + blockIdx.x;
        const float* src; half_t* dst; int Ncols, n0, k0;
        if (id < 256)      { src = Wq; dst = WqT; Ncols = 1024; n0 = (id & 15) * 64; k0 = (id >> 4) * 64; }
        else if (id < 320) { int q2 = id - 256; src = Wk; dst = WkvT; Ncols = 256; n0 = (q2 & 3) * 64; k0 = (q2 >> 2) * 64; }
        else if (id < 384) { int q2 = id - 320; src = Wv; dst = WkvT + 256 * 1024; Ncols = 256; n0 = (q2 & 3) * 64; k0 = (q2 >> 2) * 64; }
        else if (id < 640) { int q2 = id - 384; src = Wo; dst = WoT; Ncols = 1024; n0 = (q2 & 15) * 64; k0 = (q2 >> 4) * 64; }
        else if (id < 720) {
            int idx = (id - 640) * 256 + tid;
            int row = idx >> 6, col = idx & 63;
            float val = 0.f;
            if (row < 255) val = emb_t[row * 64 + col];
            else if (row >= 256 && row < 271) val = emb_f[(row - 256) * 64 + col];
            embc[idx] = (half_t)val;
            return;
        } else return;
        #pragma unroll
        for (int i2 = 0; i2 < 4; i2++) {
            int idx = i2 * 256 + tid;
            int r = idx >> 4, c4 = (idx & 15) * 4;
            *(float4*)&t[r][c4] = *(const float4*)&src[(size_t)(k0 + r) * Ncols + n0 + c4];
        }
        __syncthreads();
        #pragma unroll
        for (int i2 = 0; i2 < 2; i2++) {
            int idx = i2 * 256 + tid;
            int n = idx >> 3, kb = (idx & 7) * 8;
            half8 o;
            #pragma unroll
            for (int u = 0; u < 8; u++) o[u] = (half_t)t[kb + u][n];
            *(half8*)&dst[(size_t)(n0 + n) * 1024 + k0 + kb] = o;
        }
    }
}

// ---------------------------------------------------------------------------
// proj (512 thr, 8 waves, K-split): two 4-wave groups each GEMM half of K
// (BK=64 x 8 iters, double-buffered, register prefetch), fp32 LDS merge.
// phase 0: blocks 0..255 q-proj (fp16, x0.125*log2e), 256..383 k/v-proj
// (LDS-transpose epilogue; V written j-chunked Vp4). phase 1: out-proj.
// ---------------------------------------------------------------------------
__global__ __launch_bounds__(512) void proj(int phase,
                                            const float* __restrict__ qin,
                                            const float* __restrict__ kin,
                                            const float* __restrict__ vin,
                                            const half_t* __restrict__ AO,
                                            const half_t* __restrict__ WqT,
                                            const half_t* __restrict__ WkvT,
                                            const half_t* __restrict__ WoT,
                                            half_t* __restrict__ qs_h,
                                            half_t* __restrict__ kp_h,
                                            half_t* __restrict__ Vp4,
                                            float* __restrict__ out,
                                            float* __restrict__ out_k,
                                            float* __restrict__ out_v)
{
    __shared__ __align__(16) half_t As[2][2][64 * 72];
    __shared__ __align__(16) half_t Bs[2][2][64 * 72];
    const int id = blockIdx.x;
    int task, m0, n0;
    const float* Af = nullptr; const half_t* Ah = nullptr; const half_t* Bt;
    if (phase == 1)      { task = 2; m0 = (id >> 4) * 64; n0 = (id & 15) * 64; Ah = AO; Bt = WoT; }
    else if (id < 256)   { task = 0; m0 = (id >> 4) * 64; n0 = (id & 15) * 64; Af = qin; Bt = WqT; }
    else { task = 1; int t = id - 256; m0 = (t >> 3) * 64; n0 = (t & 7) * 64;
           Af = (n0 < 256) ? kin : vin; Bt = WkvT; }

    const int tid = threadIdx.x;
    const int kh = tid >> 8, t8 = tid & 255;
    const int w4 = (tid >> 6) & 3, l = tid & 63;
    const int quad = l >> 4, lr = l & 15, wm = w4 >> 1, wn = w4 & 1;
    const int arow = t8 >> 2, acol = (t8 & 3) * 16;
    const int kbase = kh * 512;

    {   // stage tile 0
        int kk = kbase;
        if (Af) {
            float4 f0 = *(const float4*)&Af[(size_t)(m0 + arow) * 1024 + kk + acol];
            float4 f1 = *(const float4*)&Af[(size_t)(m0 + arow) * 1024 + kk + acol + 4];
            float4 f2 = *(const float4*)&Af[(size_t)(m0 + arow) * 1024 + kk + acol + 8];
            float4 f3 = *(const float4*)&Af[(size_t)(m0 + arow) * 1024 + kk + acol + 12];
            half8 h0, h1;
            h0[0]=(half_t)f0.x; h0[1]=(half_t)f0.y; h0[2]=(half_t)f0.z; h0[3]=(half_t)f0.w;
            h0[4]=(half_t)f1.x; h0[5]=(half_t)f1.y; h0[6]=(half_t)f1.z; h0[7]=(half_t)f1.w;
            h1[0]=(half_t)f2.x; h1[1]=(half_t)f2.y; h1[2]=(half_t)f2.z; h1[3]=(half_t)f2.w;
            h1[4]=(half_t)f3.x; h1[5]=(half_t)f3.y; h1[6]=(half_t)f3.z; h1[7]=(half_t)f3.w;
            *(half8*)&As[kh][0][arow * 72 + acol] = h0;
            *(half8*)&As[kh][0][arow * 72 + acol + 8] = h1;
        } else {
            *(half8*)&As[kh][0][arow * 72 + acol]     = *(const half8*)&Ah[(size_t)(m0 + arow) * 1024 + kk + acol];
            *(half8*)&As[kh][0][arow * 72 + acol + 8] = *(const half8*)&Ah[(size_t)(m0 + arow) * 1024 + kk + acol + 8];
        }
        *(half8*)&Bs[kh][0][arow * 72 + acol]     = *(const half8*)&Bt[(size_t)(n0 + arow) * 1024 + kk + acol];
        *(half8*)&Bs[kh][0][arow * 72 + acol + 8] = *(const half8*)&Bt[(size_t)(n0 + arow) * 1024 + kk + acol + 8];
    }
    __syncthreads();

    floatx4 zero = {0.f, 0.f, 0.f, 0.f};
    floatx4 acc[2][2];
    acc[0][0] = zero; acc[0][1] = zero; acc[1][0] = zero; acc[1][1] = zero;

    float4 pf0, pf1, pf2, pf3; half8 ph0, ph1, pb0, pb1;
    for (int it = 0; it < 8; ++it) {
        if (it < 7) {
            int kk = kbase + (it + 1) * 64;
            if (Af) {
                pf0 = *(const float4*)&Af[(size_t)(m0 + arow) * 1024 + kk + acol];
                pf1 = *(const float4*)&Af[(size_t)(m0 + arow) * 1024 + kk + acol + 4];
                pf2 = *(const float4*)&Af[(size_t)(m0 + arow) * 1024 + kk + acol + 8];
                pf3 = *(const float4*)&Af[(size_t)(m0 + arow) * 1024 + kk + acol + 12];
            } else {
                ph0 = *(const half8*)&Ah[(size_t)(m0 + arow) * 1024 + kk + acol];
                ph1 = *(const half8*)&Ah[(size_t)(m0 + arow) * 1024 + kk + acol + 8];
            }
            pb0 = *(const half8*)&Bt[(size_t)(n0 + arow) * 1024 + kk + acol];
            pb1 = *(const half8*)&Bt[(size_t)(n0 + arow) * 1024 + kk + acol + 8];
        }
        const half_t* Ab = &As[kh][it & 1][0];
        const half_t* Bb = &Bs[kh][it & 1][0];
        #pragma unroll
        for (int ks = 0; ks < 2; ++ks) {
            half8 a0 = *(const half8*)&Ab[(wm * 32 + lr) * 72 + ks * 32 + quad * 8];
            half8 a1 = *(const half8*)&Ab[(wm * 32 + 16 + lr) * 72 + ks * 32 + quad * 8];
            half8 b0 = *(const half8*)&Bb[(wn * 32 + lr) * 72 + ks * 32 + quad * 8];
            half8 b1 = *(const half8*)&Bb[(wn * 32 + 16 + lr) * 72 + ks * 32 + quad * 8];
            acc[0][0] = mfma16(a0, b0, acc[0][0]);
            acc[0][1] = mfma16(a0, b1, acc[0][1]);
            acc[1][0] = mfma16(a1, b0, acc[1][0]);
            acc[1][1] = mfma16(a1, b1, acc[1][1]);
        }
        __syncthreads();
        if (it < 7) {
            int buf = (it + 1) & 1;
            if (Af) {
                half8 h0, h1;
                h0[0]=(half_t)pf0.x; h0[1]=(half_t)pf0.y; h0[2]=(half_t)pf0.z; h0[3]=(half_t)pf0.w;
                h0[4]=(half_t)pf1.x; h0[5]=(half_t)pf1.y; h0[6]=(half_t)pf1.z; h0[7]=(half_t)pf1.w;
                h1[0]=(half_t)pf2.x; h1[1]=(half_t)pf2.y; h1[2]=(half_t)pf2.z; h1[3]=(half_t)pf2.w;
                h1[4]=(half_t)pf3.x; h1[5]=(half_t)pf3.y; h1[6]=(half_t)pf3.z; h1[7]=(half_t)pf3.w;
                *(half8*)&As[kh][buf][arow * 72 + acol] = h0;
                *(half8*)&As[kh][buf][arow * 72 + acol + 8] = h1;
            } else {
                *(half8*)&As[kh][buf][arow * 72 + acol] = ph0;
                *(half8*)&As[kh][buf][arow * 72 + acol + 8] = ph1;
            }
            *(half8*)&Bs[kh][buf][arow * 72 + acol] = pb0;
            *(half8*)&Bs[kh][buf][arow * 72 + acol + 8] = pb1;
            __syncthreads();
        }
    }

    // merge K-halves (kh1 -> LDS fp32, kh0 adds)
    float* M = (float*)&Bs[0][0][0];   // 64 x 66 floats
    if (kh == 1) {
        #pragma unroll
        for (int mi = 0; mi < 2; mi++)
            #pragma unroll
            for (int ni = 0; ni < 2; ni++)
                #pragma unroll
                for (int r = 0; r < 4; r++)
                    M[(wm * 32 + mi * 16 + quad * 4 + r) * 66 + wn * 32 + ni * 16 + lr] = acc[mi][ni][r];
    }
    __syncthreads();
    if (kh == 0) {
        #pragma unroll
        for (int mi = 0; mi < 2; mi++)
            #pragma unroll
            for (int ni = 0; ni < 2; ni++)
                #pragma unroll
                for (int r = 0; r < 4; r++)
                    acc[mi][ni][r] += M[(wm * 32 + mi * 16 + quad * 4 + r) * 66 + wn * 32 + ni * 16 + lr];
    }

    if (task == 0) {
        if (kh == 0) {
            #pragma unroll
            for (int mi = 0; mi < 2; mi++)
                #pragma unroll
                for (int ni = 0; ni < 2; ni++)
                    #pragma unroll
                    for (int r = 0; r < 4; r++) {
                        int m = m0 + wm * 32 + mi * 16 + quad * 4 + r;
                        int n = n0 + wn * 32 + ni * 16 + lr;
                        qs_h[(size_t)m * 1024 + n] = (half_t)(acc[mi][ni][r] * (0.125f * LOG2E));
                    }
        }
    } else if (task == 2) {
        if (kh == 0) {
            #pragma unroll
            for (int mi = 0; mi < 2; mi++)
                #pragma unroll
                for (int ni = 0; ni < 2; ni++)
                    #pragma unroll
                    for (int r = 0; r < 4; r++) {
                        int m = m0 + wm * 32 + mi * 16 + quad * 4 + r;
                        int n = n0 + wn * 32 + ni * 16 + lr;
                        out[(size_t)m * 1024 + n] = acc[mi][ni][r];
                    }
        }
    } else {
        float* Ct = (float*)&As[0][0][0];   // 64 x 68 floats (transposed acc)
        if (kh == 0) {
            #pragma unroll
            for (int mi = 0; mi < 2; mi++)
                #pragma unroll
                for (int ni = 0; ni < 2; ni++)
                    #pragma unroll
                    for (int r = 0; r < 4; r++)
                        Ct[(wn * 32 + ni * 16 + lr) * 68 + wm * 32 + mi * 16 + quad * 4 + r] = acc[mi][ni][r];
        }
        __syncthreads();
        if (kh == 0) {
            const int b = m0 >> 9, jm0 = m0 & 511;
            if (n0 < 256) {
                int gg = n0 >> 6;
                {
                    int d = t8 >> 2, jc = (t8 & 3) * 16;
                    float4 vv[4];
                    #pragma unroll
                    for (int u = 0; u < 4; u++) vv[u] = *(float4*)&Ct[d * 68 + jc + u * 4];
                    #pragma unroll
                    for (int t = 0; t < 4; t++)
                        #pragma unroll
                        for (int u = 0; u < 4; u++)
                            *(float4*)&out_k[((size_t)((b * 16 + gg * 4 + t) * 64 + d)) * 1536 + 1024 + jm0 + jc + u * 4] = vv[u];
                }
                {
                    int j = t8 >> 2, dc = (t8 & 3) * 16;
                    half8 o0, o1;
                    #pragma unroll
                    for (int u = 0; u < 8; u++) o0[u] = (half_t)Ct[(dc + u) * 68 + j];
                    #pragma unroll
                    for (int u = 0; u < 8; u++) o1[u] = (half_t)Ct[(dc + 8 + u) * 68 + j];
                    *(half8*)&kp_h[((size_t)(b * 512 + jm0 + j)) * 256 + n0 + dc] = o0;
                    *(half8*)&kp_h[((size_t)(b * 512 + jm0 + j)) * 256 + n0 + dc + 8] = o1;
                }
            } else {
                int gg = (n0 - 256) >> 6;
                {
                    int j = t8 >> 2, dc = (t8 & 3) * 16;
                    float4 vv[4];
                    #pragma unroll
                    for (int u = 0; u < 4; u++) {
                        float4 x;
                        x.x = Ct[(dc + u * 4 + 0) * 68 + j];
                        x.y = Ct[(dc + u * 4 + 1) * 68 + j];
                        x.z = Ct[(dc + u * 4 + 2) * 68 + j];
                        x.w = Ct[(dc + u * 4 + 3) * 68 + j];
                        vv[u] = x;
                    }
                    #pragma unroll
                    for (int t = 0; t < 4; t++)
                        #pragma unroll
                        for (int u = 0; u < 4; u++)
                            *(float4*)&out_v[(((size_t)(b * 16 + gg * 4 + t) * 1536) + 1024 + jm0 + j) * 64 + dc + u * 4] = vv[u];
                }
                {   // Vp4[(b*4+gg)][jc'][d][4], jc' = (jm0+jc16)/4 + u
                    int d = t8 >> 2, jc16 = (t8 & 3) * 16;
                    #pragma unroll
                    for (int u = 0; u < 4; u++) {
                        half4v o;
                        #pragma unroll
                        for (int s2 = 0; s2 < 4; s2++) o[s2] = (half_t)Ct[d * 68 + jc16 + u * 4 + s2];
                        *(half4v*)&Vp4[(((size_t)(b * 4 + gg) * 128 + ((jm0 + jc16) >> 2) + u) * 64 + d) * 4] = o;
                    }
                }
            }
        }
    }
}

// ---------------------------------------------------------------------------
// Flash v6: barrier-free main loop. 512 thr / 8 waves; wave jh owns 16 j-rows
// of each 128-j tile, all 32 i. K A-frags read DIRECTLY from global (L2: grid
// (32,16) keeps all 16 i-tiles of a bh on one XCD; 4 bh x 392KB per L2),
// prefetched one iter ahead in regs. V B-frags read from j-chunked Vc4/Vp4
// (coalesced), issued at iter top, consumed after softmax. Zero LDS traffic
// in-loop except 2 ds_read_u16 bias lookups. LDS: bt 13.4KB, reused for the
// one-time 8-way jh merge (61KB) after a post-loop barrier.
// ---------------------------------------------------------------------------
__global__ __launch_bounds__(512, 4) void flash(const half_t* __restrict__ qs_h,
                                                const half_t* __restrict__ Kc,
                                                const half_t* __restrict__ kp_h,
                                                const half_t* __restrict__ Vc4,
                                                const half_t* __restrict__ Vp4,
                                                const half_t* __restrict__ embc,
                                                half_t* __restrict__ AO)
{
    __shared__ __align__(16) unsigned char smem_raw[61824];
    half_t* bt = (half_t*)smem_raw;              // [32][210]

    const int bh = blockIdx.x, b = bh >> 4, h = bh & 15, g = h >> 2;
    const int i0 = blockIdx.y * 32;
    const int tid = threadIdx.x, jh = tid >> 6, l = tid & 63;
    const int quad = l >> 4, lr = l & 15;

    // Q frags straight from global: qf[ih][kh], row i = ih*16+lr
    half8 qf[2][2];
    #pragma unroll
    for (int ih = 0; ih < 2; ih++) {
        const half_t* qsrc = &qs_h[((size_t)(b * 512 + i0 + ih * 16 + lr)) * 1024 + h * 64];
        qf[ih][0] = *(const half8*)(qsrc + quad * 8);
        qf[ih][1] = *(const half8*)(qsrc + 32 + quad * 8);
    }

    floatx4 zero = {0.f, 0.f, 0.f, 0.f};
    // bias GEMM: bt[i][t-64] = q_i . embc[t]; wave -> (ih = jh&1, tk chunk)
    {
        int ih = jh & 1;
        for (int tk = 4 + (jh >> 1); tk < 17; tk += 4) {
            floatx4 acc = zero;
            half8 e0 = *(const half8*)&embc[(size_t)(tk * 16 + lr) * 64 + quad * 8];
            half8 e1 = *(const half8*)&embc[(size_t)(tk * 16 + lr) * 64 + 32 + quad * 8];
            acc = mfma16(e0, qf[ih][0], acc);    // D[m=t][n=i]
            acc = mfma16(e1, qf[ih][1], acc);
            #pragma unroll
            for (int r = 0; r < 4; r++)
                bt[(ih * 16 + lr) * 210 + tk * 16 + quad * 4 + r - 64] = (half_t)acc[r];
        }
    }
    __syncthreads();   // bt ready

    // per-lane constants
    float bfv[2][4];
    #pragma unroll
    for (int ih = 0; ih < 2; ih++)
        #pragma unroll
        for (int r = 0; r < 4; r++) {
            int f = (lr & 7) - ((quad & 1) * 4 + r) + 7;     // 0..14
            bfv[ih][r] = (float)bt[(ih * 16 + lr) * 210 + 192 + f];
        }
    const int qtr0 = (i0 + lr) >> 3;
    const int qtr1 = (i0 + 16 + lr) >> 3;

    floatx4 accO[2][4];
    #pragma unroll
    for (int ih = 0; ih < 2; ih++)
        #pragma unroll
        for (int ni = 0; ni < 4; ni++) accO[ih][ni] = zero;
    floatx4 accS[2];
    accS[0] = zero; accS[1] = zero;
    const half4v vone = {(half_t)1.f, (half_t)1.f, (half_t)1.f, (half_t)1.f};

    // K prefetch for jt=0 (wave's 16 rows, full 64 k)
    half8 kc0, kc1;
    {
        const half_t* kb = &Kc[((size_t)bh * 1536 + jh * 16 + lr) * 64];
        kc0 = *(const half8*)(kb + quad * 8);
        kc1 = *(const half8*)(kb + 32 + quad * 8);
    }

    for (int jt = 0; jt < 16; ++jt) {
        const int j0 = jt * 128;
        // V loads for CURRENT iter (ready by PV time)
        half4v vb[4];
        {
            const half_t* vbase; int jcb;
            if (j0 < 1536) { vbase = Vc4 + (size_t)bh * 98304;          jcb = j0 >> 2; }
            else           { vbase = Vp4 + (size_t)(b * 4 + g) * 32768; jcb = (j0 - 1536) >> 2; }
            const int jc = jcb + jh * 4 + quad;
            #pragma unroll
            for (int ni = 0; ni < 4; ni++)
                vb[ni] = *(const half4v*)&vbase[((size_t)jc * 64 + ni * 16 + lr) * 4];
        }
        // K prefetch for NEXT iter
        half8 kn0, kn1;
        if (jt < 15) {
            const int j1 = j0 + 128;
            const half_t* kb = (j1 < 1536)
                ? &Kc[((size_t)bh * 1536 + j1 + jh * 16 + lr) * 64]
                : &kp_h[((size_t)(b * 512 + j1 - 1536 + jh * 16 + lr)) * 256 + g * 64];
            kn0 = *(const half8*)(kb + quad * 8);
            kn1 = *(const half8*)(kb + 32 + quad * 8);
        }

        // S^T = K . Q^T : D[m = j-offset quad*4+r][n = i = ih*16+lr]
        floatx4 s[2];
        #pragma unroll
        for (int ih = 0; ih < 2; ih++) {
            s[ih] = mfma16(kc0, qf[ih][0], zero);
            s[ih] = mfma16(kc1, qf[ih][1], s[ih]);
        }
        // bias + exp2 (no max: scores bounded)
        const int ktb = jt * 16 + jh * 2 + (quad >> 1);
        #pragma unroll
        for (int ih = 0; ih < 2; ih++) {
            int toff = 255 + (ih ? qtr1 : qtr0) - ktb;
            toff = min(toff, 190);
            float tb = (float)bt[(ih * 16 + lr) * 210 + toff];
            #pragma unroll
            for (int r = 0; r < 4; r++)
                s[ih][r] = exp2f(s[ih][r] + tb + bfv[ih][r]);
        }
        // P -> A-frags (m=lane=i, k=quad*4+r=j) ; PV + ones-MFMA row sums
        #pragma unroll
        for (int ih = 0; ih < 2; ih++) {
            half4v pf;
            #pragma unroll
            for (int r = 0; r < 4; r++) pf[r] = (half_t)s[ih][r];
            accS[ih] = mfma16x16(pf, vone, accS[ih]);
            #pragma unroll
            for (int ni = 0; ni < 4; ni++)
                accO[ih][ni] = mfma16x16(pf, vb[ni], accO[ih][ni]);
        }
        if (jt < 15) { kc0 = kn0; kc1 = kn1; }
    }

    // 8-way jh merge in LDS (bt dead after this barrier)
    __syncthreads();
    float* Mf = (float*)smem_raw;          // 7 partials x 32 x 68 fp32
    float* Sf = Mf + 7 * 32 * 68;          // 7 x 32 fp32
    if (jh != 0) {
        const int p = jh - 1;
        #pragma unroll
        for (int ih = 0; ih < 2; ih++) {
            #pragma unroll
            for (int ni = 0; ni < 4; ni++)
                #pragma unroll
                for (int r = 0; r < 4; r++)
                    Mf[(p * 32 + ih * 16 + quad * 4 + r) * 68 + ni * 16 + lr] = accO[ih][ni][r];
            if (lr == 0) {
                #pragma unroll
                for (int r = 0; r < 4; r++)
                    Sf[p * 32 + ih * 16 + quad * 4 + r] = accS[ih][r];
            }
        }
    }
    __syncthreads();
    if (jh == 0) {
        #pragma unroll
        for (int ih = 0; ih < 2; ih++) {
            float inv[4];
            #pragma unroll
            for (int r = 0; r < 4; r++) {
                float t = accS[ih][r];
                #pragma unroll
                for (int p = 0; p < 7; p++) t += Sf[p * 32 + ih * 16 + quad * 4 + r];
                inv[r] = 1.0f / t;
            }
            #pragma unroll
            for (int ni = 0; ni < 4; ni++)
                #pragma unroll
                for (int r = 0; r < 4; r++) {
                    float o = accO[ih][ni][r];
                    #pragma unroll
                    for (int p = 0; p < 7; p++)
                        o += Mf[(p * 32 + ih * 16 + quad * 4 + r) * 68 + ni * 16 + lr];
                    int row = ih * 16 + quad * 4 + r;
                    AO[((size_t)(b * 512 + i0 + row)) * 1024 + h * 64 + ni * 16 + lr] =
                        (half_t)(o * inv[r]);
                }
        }
    }
}

// ---------------------------------------------------------------------------
extern "C" void kernel_launch(void* const* d_in, const int* in_sizes, int n_in,
                              void* d_out, int out_size, void* d_ws, size_t ws_size,
                              hipStream_t stream)
{
    const float* q       = (const float*)d_in[0];
    const float* k       = (const float*)d_in[1];
    const float* v       = (const float*)d_in[2];
    const float* cache_k = (const float*)d_in[3];
    const float* cache_v = (const float*)d_in[4];
    const float* Wq      = (const float*)d_in[5];
    const float* Wk      = (const float*)d_in[6];
    const float* Wv      = (const float*)d_in[7];
    const float* Wo      = (const float*)d_in[8];
    const float* emb_t   = (const float*)d_in[9];
    const float* emb_f   = (const float*)d_in[10];

    float* out   = (float*)d_out;                 // (2,512,1024)
    float* out_k = out + 1048576;                 // (32,64,1536)
    float* out_v = out_k + 3145728;               // (32,1536,64)

    half_t* ws = (half_t*)d_ws;
    half_t* qs_h = ws;                  // 1048576
    half_t* kp_h = ws + 1048576;        //  262144
    half_t* Vp4  = ws + 1310720;        //  262144  (2*4 groups)[128][64][4]
    half_t* Kc   = ws + 1572864;        // 3145728
    half_t* Vc4  = ws + 4718592;        // 3145728  [32][384][64][4]
    half_t* WqT  = ws + 7864320;        // 1048576
    half_t* WkvT = ws + 8912896;        //  524288
    half_t* WoT  = ws + 9437184;        // 1048576
    half_t* embc = ws + 10485760;       //   20480
    half_t* AO   = ws + 10506240;       // 1048576

    prep<<<dim3(24, 32, 3), 256, 0, stream>>>(cache_k, cache_v, Wq, Wk, Wv, Wo,
                                              emb_t, emb_f, Kc, Vc4, out_k, out_v,
                                              WqT, WkvT, WoT, embc);
    proj<<<dim3(384), 512, 0, stream>>>(0, q, k, v, nullptr, WqT, WkvT, WoT,
                                        qs_h, kp_h, Vp4, out, out_k, out_v);
    flash<<<dim3(32, 16), 512, 0, stream>>>(qs_h, Kc, kp_h, Vc4, Vp4, embc, AO);
    proj<<<dim3(256), 512, 0, stream>>>(1, q, k, v, AO, WqT, WkvT, WoT,
                                        qs_h, kp_h, Vp4, out, out_k, out_v);
}

// Round 3
// 169.053 us; speedup vs baseline: 1.0336x; 1.0336x over previous
//
#include <hip/hip_runtime.h>
#include <math.h>

typedef _Float16 half_t;
typedef _Float16 half8  __attribute__((ext_vector_type(8)));
typedef _Float16 half4v __attribute__((ext_vector_type(4)));
typedef float    floatx4 __attribute__((ext_vector_type(4)));

#define LOG2E 1.44269504088896f

static __device__ __forceinline__ floatx4 mfma16(half8 a, half8 b, floatx4 c) {
    return __builtin_amdgcn_mfma_f32_16x16x32_f16(a, b, c, 0, 0, 0);
}
static __device__ __forceinline__ floatx4 mfma16x16(half4v a, half4v b, floatx4 c) {
    return __builtin_amdgcn_mfma_f32_16x16x16f16(a, b, c, 0, 0, 0);
}

// ---------------------------------------------------------------------------
// prepw (256 thr, 720 blocks): weight transposes + embc build only.
// (cache transposes moved into stage1 -- they don't feed proj0.)
// ---------------------------------------------------------------------------
__global__ __launch_bounds__(256) void prepw(const float* __restrict__ Wq,
                                             const float* __restrict__ Wk,
                                             const float* __restrict__ Wv,
                                             const float* __restrict__ Wo,
                                             const float* __restrict__ emb_t,
                                             const float* __restrict__ emb_f,
                                             half_t* __restrict__ WqT,
                                             half_t* __restrict__ WkvT,
                                             half_t* __restrict__ WoT,
                                             half_t* __restrict__ embc)
{
    const int tid = threadIdx.x;
    const int id = blockIdx.x;
    __shared__ float t[64][65];
    const float* src; half_t* dst; int Ncols, n0, k0;
    if (id < 256)      { src = Wq; dst = WqT; Ncols = 1024; n0 = (id & 15) * 64; k0 = (id >> 4) * 64; }
    else if (id < 320) { int q2 = id - 256; src = Wk; dst = WkvT; Ncols = 256; n0 = (q2 & 3) * 64; k0 = (q2 >> 2) * 64; }
    else if (id < 384) { int q2 = id - 320; src = Wv; dst = WkvT + 256 * 1024; Ncols = 256; n0 = (q2 & 3) * 64; k0 = (q2 >> 2) * 64; }
    else if (id < 640) { int q2 = id - 384; src = Wo; dst = WoT; Ncols = 1024; n0 = (q2 & 15) * 64; k0 = (q2 >> 4) * 64; }
    else {
        int idx = (id - 640) * 256 + tid;
        int row = idx >> 6, col = idx & 63;
        float val = 0.f;
        if (row < 255) val = emb_t[row * 64 + col];
        else if (row >= 256 && row < 271) val = emb_f[(row - 256) * 64 + col];
        embc[idx] = (half_t)val;
        return;
    }
    #pragma unroll
    for (int i2 = 0; i2 < 4; i2++) {
        int idx = i2 * 256 + tid;
        int r = idx >> 4, c4 = (idx & 15) * 4;
        *(float4*)&t[r][c4] = *(const float4*)&src[(size_t)(k0 + r) * Ncols + n0 + c4];
    }
    __syncthreads();
    #pragma unroll
    for (int i2 = 0; i2 < 2; i2++) {
        int idx = i2 * 256 + tid;
        int n = idx >> 3, kb = (idx & 7) * 8;
        half8 o;
        #pragma unroll
        for (int u = 0; u < 8; u++) o[u] = (half_t)t[kb + u][n];
        *(half8*)&dst[(size_t)(n0 + n) * 1024 + k0 + kb] = o;
    }
}

// ---------------------------------------------------------------------------
// proj_core: 512-thr 64x64-tile GEMM, K=1024 split into two 4-wave halves
// (BK=64 x 8 iters, double-buffered, register prefetch), fp32 LDS merge.
// task 0: q-proj (fp16 out, x0.125*log2e). task 1: k/v-proj (transpose
// epilogues, V j-chunked Vp4). task 2: out-proj (fp32 out).
// Needs 73728 B of LDS at sm.
// ---------------------------------------------------------------------------
static __device__ __forceinline__ void proj_core(int task, int m0, int n0,
                                                 const float* __restrict__ Af,
                                                 const half_t* __restrict__ Ah,
                                                 const half_t* __restrict__ Bt,
                                                 half_t* __restrict__ qs_h,
                                                 half_t* __restrict__ kp_h,
                                                 half_t* __restrict__ Vp4,
                                                 float* __restrict__ out,
                                                 float* __restrict__ out_k,
                                                 float* __restrict__ out_v,
                                                 half_t* sm, int tid)
{
    half_t* As = sm;                 // [kh][buf][64*72]
    half_t* Bs = sm + 4 * 4608;

    const int kh = tid >> 8, t8 = tid & 255;
    const int w4 = (tid >> 6) & 3, l = tid & 63;
    const int quad = l >> 4, lr = l & 15, wm = w4 >> 1, wn = w4 & 1;
    const int arow = t8 >> 2, acol = (t8 & 3) * 16;
    const int kbase = kh * 512;
    half_t* Ak = As + kh * 2 * 4608;
    half_t* Bk = Bs + kh * 2 * 4608;

    {   // stage tile 0
        int kk = kbase;
        if (Af) {
            float4 f0 = *(const float4*)&Af[(size_t)(m0 + arow) * 1024 + kk + acol];
            float4 f1 = *(const float4*)&Af[(size_t)(m0 + arow) * 1024 + kk + acol + 4];
            float4 f2 = *(const float4*)&Af[(size_t)(m0 + arow) * 1024 + kk + acol + 8];
            float4 f3 = *(const float4*)&Af[(size_t)(m0 + arow) * 1024 + kk + acol + 12];
            half8 h0, h1;
            h0[0]=(half_t)f0.x; h0[1]=(half_t)f0.y; h0[2]=(half_t)f0.z; h0[3]=(half_t)f0.w;
            h0[4]=(half_t)f1.x; h0[5]=(half_t)f1.y; h0[6]=(half_t)f1.z; h0[7]=(half_t)f1.w;
            h1[0]=(half_t)f2.x; h1[1]=(half_t)f2.y; h1[2]=(half_t)f2.z; h1[3]=(half_t)f2.w;
            h1[4]=(half_t)f3.x; h1[5]=(half_t)f3.y; h1[6]=(half_t)f3.z; h1[7]=(half_t)f3.w;
            *(half8*)&Ak[arow * 72 + acol] = h0;
            *(half8*)&Ak[arow * 72 + acol + 8] = h1;
        } else {
            *(half8*)&Ak[arow * 72 + acol]     = *(const half8*)&Ah[(size_t)(m0 + arow) * 1024 + kk + acol];
            *(half8*)&Ak[arow * 72 + acol + 8] = *(const half8*)&Ah[(size_t)(m0 + arow) * 1024 + kk + acol + 8];
        }
        *(half8*)&Bk[arow * 72 + acol]     = *(const half8*)&Bt[(size_t)(n0 + arow) * 1024 + kk + acol];
        *(half8*)&Bk[arow * 72 + acol + 8] = *(const half8*)&Bt[(size_t)(n0 + arow) * 1024 + kk + acol + 8];
    }
    __syncthreads();

    floatx4 zero = {0.f, 0.f, 0.f, 0.f};
    floatx4 acc[2][2];
    acc[0][0] = zero; acc[0][1] = zero; acc[1][0] = zero; acc[1][1] = zero;

    float4 pf0, pf1, pf2, pf3; half8 ph0, ph1, pb0, pb1;
    for (int it = 0; it < 8; ++it) {
        if (it < 7) {
            int kk = kbase + (it + 1) * 64;
            if (Af) {
                pf0 = *(const float4*)&Af[(size_t)(m0 + arow) * 1024 + kk + acol];
                pf1 = *(const float4*)&Af[(size_t)(m0 + arow) * 1024 + kk + acol + 4];
                pf2 = *(const float4*)&Af[(size_t)(m0 + arow) * 1024 + kk + acol + 8];
                pf3 = *(const float4*)&Af[(size_t)(m0 + arow) * 1024 + kk + acol + 12];
            } else {
                ph0 = *(const half8*)&Ah[(size_t)(m0 + arow) * 1024 + kk + acol];
                ph1 = *(const half8*)&Ah[(size_t)(m0 + arow) * 1024 + kk + acol + 8];
            }
            pb0 = *(const half8*)&Bt[(size_t)(n0 + arow) * 1024 + kk + acol];
            pb1 = *(const half8*)&Bt[(size_t)(n0 + arow) * 1024 + kk + acol + 8];
        }
        const half_t* Ab = Ak + (it & 1) * 4608;
        const half_t* Bb = Bk + (it & 1) * 4608;
        #pragma unroll
        for (int ks = 0; ks < 2; ++ks) {
            half8 a0 = *(const half8*)&Ab[(wm * 32 + lr) * 72 + ks * 32 + quad * 8];
            half8 a1 = *(const half8*)&Ab[(wm * 32 + 16 + lr) * 72 + ks * 32 + quad * 8];
            half8 b0 = *(const half8*)&Bb[(wn * 32 + lr) * 72 + ks * 32 + quad * 8];
            half8 b1 = *(const half8*)&Bb[(wn * 32 + 16 + lr) * 72 + ks * 32 + quad * 8];
            acc[0][0] = mfma16(a0, b0, acc[0][0]);
            acc[0][1] = mfma16(a0, b1, acc[0][1]);
            acc[1][0] = mfma16(a1, b0, acc[1][0]);
            acc[1][1] = mfma16(a1, b1, acc[1][1]);
        }
        __syncthreads();
        if (it < 7) {
            int buf = (it + 1) & 1;
            if (Af) {
                half8 h0, h1;
                h0[0]=(half_t)pf0.x; h0[1]=(half_t)pf0.y; h0[2]=(half_t)pf0.z; h0[3]=(half_t)pf0.w;
                h0[4]=(half_t)pf1.x; h0[5]=(half_t)pf1.y; h0[6]=(half_t)pf1.z; h0[7]=(half_t)pf1.w;
                h1[0]=(half_t)pf2.x; h1[1]=(half_t)pf2.y; h1[2]=(half_t)pf2.z; h1[3]=(half_t)pf2.w;
                h1[4]=(half_t)pf3.x; h1[5]=(half_t)pf3.y; h1[6]=(half_t)pf3.z; h1[7]=(half_t)pf3.w;
                *(half8*)&Ak[buf * 4608 + arow * 72 + acol] = h0;
                *(half8*)&Ak[buf * 4608 + arow * 72 + acol + 8] = h1;
            } else {
                *(half8*)&Ak[buf * 4608 + arow * 72 + acol] = ph0;
                *(half8*)&Ak[buf * 4608 + arow * 72 + acol + 8] = ph1;
            }
            *(half8*)&Bk[buf * 4608 + arow * 72 + acol] = pb0;
            *(half8*)&Bk[buf * 4608 + arow * 72 + acol + 8] = pb1;
            __syncthreads();
        }
    }

    // merge K-halves (kh1 -> LDS fp32, kh0 adds)
    float* M = (float*)Bs;   // 64 x 66 floats
    if (kh == 1) {
        #pragma unroll
        for (int mi = 0; mi < 2; mi++)
            #pragma unroll
            for (int ni = 0; ni < 2; ni++)
                #pragma unroll
                for (int r = 0; r < 4; r++)
                    M[(wm * 32 + mi * 16 + quad * 4 + r) * 66 + wn * 32 + ni * 16 + lr] = acc[mi][ni][r];
    }
    __syncthreads();
    if (kh == 0) {
        #pragma unroll
        for (int mi = 0; mi < 2; mi++)
            #pragma unroll
            for (int ni = 0; ni < 2; ni++)
                #pragma unroll
                for (int r = 0; r < 4; r++)
                    acc[mi][ni][r] += M[(wm * 32 + mi * 16 + quad * 4 + r) * 66 + wn * 32 + ni * 16 + lr];
    }

    if (task == 0) {
        if (kh == 0) {
            #pragma unroll
            for (int mi = 0; mi < 2; mi++)
                #pragma unroll
                for (int ni = 0; ni < 2; ni++)
                    #pragma unroll
                    for (int r = 0; r < 4; r++) {
                        int m = m0 + wm * 32 + mi * 16 + quad * 4 + r;
                        int n = n0 + wn * 32 + ni * 16 + lr;
                        qs_h[(size_t)m * 1024 + n] = (half_t)(acc[mi][ni][r] * (0.125f * LOG2E));
                    }
        }
    } else if (task == 2) {
        if (kh == 0) {
            #pragma unroll
            for (int mi = 0; mi < 2; mi++)
                #pragma unroll
                for (int ni = 0; ni < 2; ni++)
                    #pragma unroll
                    for (int r = 0; r < 4; r++) {
                        int m = m0 + wm * 32 + mi * 16 + quad * 4 + r;
                        int n = n0 + wn * 32 + ni * 16 + lr;
                        out[(size_t)m * 1024 + n] = acc[mi][ni][r];
                    }
        }
    } else {
        float* Ct = (float*)As;   // 64 x 68 floats (transposed acc)
        if (kh == 0) {
            #pragma unroll
            for (int mi = 0; mi < 2; mi++)
                #pragma unroll
                for (int ni = 0; ni < 2; ni++)
                    #pragma unroll
                    for (int r = 0; r < 4; r++)
                        Ct[(wn * 32 + ni * 16 + lr) * 68 + wm * 32 + mi * 16 + quad * 4 + r] = acc[mi][ni][r];
        }
        __syncthreads();
        if (kh == 0) {
            const int b = m0 >> 9, jm0 = m0 & 511;
            if (n0 < 256) {
                int gg = n0 >> 6;
                {
                    int d = t8 >> 2, jc = (t8 & 3) * 16;
                    float4 vv[4];
                    #pragma unroll
                    for (int u = 0; u < 4; u++) vv[u] = *(float4*)&Ct[d * 68 + jc + u * 4];
                    #pragma unroll
                    for (int t = 0; t < 4; t++)
                        #pragma unroll
                        for (int u = 0; u < 4; u++)
                            *(float4*)&out_k[((size_t)((b * 16 + gg * 4 + t) * 64 + d)) * 1536 + 1024 + jm0 + jc + u * 4] = vv[u];
                }
                {
                    int j = t8 >> 2, dc = (t8 & 3) * 16;
                    half8 o0, o1;
                    #pragma unroll
                    for (int u = 0; u < 8; u++) o0[u] = (half_t)Ct[(dc + u) * 68 + j];
                    #pragma unroll
                    for (int u = 0; u < 8; u++) o1[u] = (half_t)Ct[(dc + 8 + u) * 68 + j];
                    *(half8*)&kp_h[((size_t)(b * 512 + jm0 + j)) * 256 + n0 + dc] = o0;
                    *(half8*)&kp_h[((size_t)(b * 512 + jm0 + j)) * 256 + n0 + dc + 8] = o1;
                }
            } else {
                int gg = (n0 - 256) >> 6;
                {
                    int j = t8 >> 2, dc = (t8 & 3) * 16;
                    float4 vv[4];
                    #pragma unroll
                    for (int u = 0; u < 4; u++) {
                        float4 x;
                        x.x = Ct[(dc + u * 4 + 0) * 68 + j];
                        x.y = Ct[(dc + u * 4 + 1) * 68 + j];
                        x.z = Ct[(dc + u * 4 + 2) * 68 + j];
                        x.w = Ct[(dc + u * 4 + 3) * 68 + j];
                        vv[u] = x;
                    }
                    #pragma unroll
                    for (int t = 0; t < 4; t++)
                        #pragma unroll
                        for (int u = 0; u < 4; u++)
                            *(float4*)&out_v[(((size_t)(b * 16 + gg * 4 + t) * 1536) + 1024 + jm0 + j) * 64 + dc + u * 4] = vv[u];
                }
                {   // Vp4[(b*4+gg)][jc'][d][4]
                    int d = t8 >> 2, jc16 = (t8 & 3) * 16;
                    #pragma unroll
                    for (int u = 0; u < 4; u++) {
                        half4v o;
                        #pragma unroll
                        for (int s2 = 0; s2 < 4; s2++) o[s2] = (half_t)Ct[d * 68 + jc16 + u * 4 + s2];
                        *(half4v*)&Vp4[(((size_t)(b * 4 + gg) * 128 + ((jm0 + jc16) >> 2) + u) * 64 + d) * 4] = o;
                    }
                }
            }
        }
    }
}

// ---------------------------------------------------------------------------
// stage1 (512 thr, 1152 blocks): blocks [0,384) = q/k/v projection GEMMs
// (proj_core task 0/1); blocks [384,1152) = cache transposes, two 256-thr
// units per block: sub 0 = cache_k -> Kc + out_k shift, sub 1 = cache_v ->
// Vc4 + out_v shift (independent of proj0 -- overlap memory with MFMA).
// ---------------------------------------------------------------------------
__global__ __launch_bounds__(512) void stage1(const float* __restrict__ qin,
                                              const float* __restrict__ kin,
                                              const float* __restrict__ vin,
                                              const float* __restrict__ cache_k,
                                              const float* __restrict__ cache_v,
                                              const half_t* __restrict__ WqT,
                                              const half_t* __restrict__ WkvT,
                                              half_t* __restrict__ qs_h,
                                              half_t* __restrict__ kp_h,
                                              half_t* __restrict__ Vp4,
                                              half_t* __restrict__ Kc,
                                              half_t* __restrict__ Vc4,
                                              float* __restrict__ out_k,
                                              float* __restrict__ out_v)
{
    __shared__ __align__(16) unsigned char sm[73728];
    const int bid = blockIdx.x;
    const int tid = threadIdx.x;

    if (bid < 384) {
        int task, m0, n0;
        const float* Af; const half_t* Bt;
        if (bid < 256) { task = 0; m0 = (bid >> 4) * 64; n0 = (bid & 15) * 64; Af = qin; Bt = WqT; }
        else { task = 1; int t = bid - 256; m0 = (t >> 3) * 64; n0 = (t & 7) * 64;
               Af = (n0 < 256) ? kin : vin; Bt = WkvT; }
        proj_core(task, m0, n0, Af, nullptr, Bt, qs_h, kp_h, Vp4,
                  nullptr, out_k, out_v, (half_t*)sm, tid);
        return;
    }

    // cache transposes: sub 0 = K, sub 1 = V (same bx/by, same barrier count)
    const int nb = bid - 384;                    // 0..767
    const int sub = tid >> 8, tl = tid & 255;
    const int bx = nb % 24, by = nb / 24;        // j-tile, bh
    const int bh = by, j0 = bx * 64;
    const bool shift = (j0 >= 512);
    float (*t)[65] = (float(*)[65])(sm + sub * 16640);

    if (sub == 0) {
        #pragma unroll
        for (int i2 = 0; i2 < 4; i2++) {
            int idx = i2 * 256 + tl;
            int d = idx >> 4, j4 = (idx & 15) * 4;
            float4 vv = *(const float4*)&cache_k[((size_t)bh * 64 + d) * 1536 + j0 + j4];
            *(float4*)&t[d][j4] = vv;
            if (shift) *(float4*)&out_k[((size_t)bh * 64 + d) * 1536 + j0 - 512 + j4] = vv;
        }
    } else {
        #pragma unroll
        for (int i2 = 0; i2 < 4; i2++) {
            int idx = i2 * 256 + tl;
            int j = idx >> 4, d4 = (idx & 15) * 4;
            float4 vv = *(const float4*)&cache_v[((size_t)bh * 1536 + j0 + j) * 64 + d4];
            *(float4*)&t[j][d4] = vv;
            if (shift) *(float4*)&out_v[((size_t)bh * 1536 + j0 + j - 512) * 64 + d4] = vv;
        }
    }
    __syncthreads();
    if (sub == 0) {
        #pragma unroll
        for (int i2 = 0; i2 < 2; i2++) {
            int idx = i2 * 256 + tl;
            int j = idx >> 3, db = (idx & 7) * 8;
            half8 o;
            #pragma unroll
            for (int u = 0; u < 8; u++) o[u] = (half_t)t[db + u][j];
            *(half8*)&Kc[((size_t)bh * 1536 + j0 + j) * 64 + db] = o;
        }
    } else {
        // Vc4[bh][jc][d][4]: half4 per (jc,d), d fastest (coalesced)
        #pragma unroll
        for (int i2 = 0; i2 < 4; i2++) {
            int idx = i2 * 256 + tl;             // 0..1023
            int jc = idx >> 6, d = idx & 63;     // jc 0..15 local
            half4v o;
            #pragma unroll
            for (int u = 0; u < 4; u++) o[u] = (half_t)t[jc * 4 + u][d];
            *(half4v*)&Vc4[(((size_t)bh * 384 + (j0 >> 2) + jc) * 64 + d) * 4] = o;
        }
    }
}

// ---------------------------------------------------------------------------
// proj1 (512 thr, 256 blocks): out-projection AO @ WoT -> fp32 out.
// ---------------------------------------------------------------------------
__global__ __launch_bounds__(512) void proj1(const half_t* __restrict__ AO,
                                             const half_t* __restrict__ WoT,
                                             float* __restrict__ out)
{
    __shared__ __align__(16) unsigned char sm[73728];
    const int id = blockIdx.x;
    const int m0 = (id >> 4) * 64, n0 = (id & 15) * 64;
    proj_core(2, m0, n0, nullptr, AO, WoT, nullptr, nullptr, nullptr,
              out, nullptr, nullptr, (half_t*)sm, threadIdx.x);
}

// ---------------------------------------------------------------------------
// Flash v7: barrier-free main loop, K AND V prefetched one iter ahead in
// registers (v6 loaded V same-iter -> exposed L2 latency). 512 thr / 8 waves;
// wave jh owns 16 j-rows of each 128-j tile, all 32 i. Zero in-loop LDS
// traffic except bias ds_read_u16. One-time 8-way jh merge in LDS.
// ---------------------------------------------------------------------------
__global__ __launch_bounds__(512, 4) void flash(const half_t* __restrict__ qs_h,
                                                const half_t* __restrict__ Kc,
                                                const half_t* __restrict__ kp_h,
                                                const half_t* __restrict__ Vc4,
                                                const half_t* __restrict__ Vp4,
                                                const half_t* __restrict__ embc,
                                                half_t* __restrict__ AO)
{
    __shared__ __align__(16) unsigned char smem_raw[61824];
    half_t* bt = (half_t*)smem_raw;              // [32][210]

    const int bh = blockIdx.x, b = bh >> 4, h = bh & 15, g = h >> 2;
    const int i0 = blockIdx.y * 32;
    const int tid = threadIdx.x, jh = tid >> 6, l = tid & 63;
    const int quad = l >> 4, lr = l & 15;

    // Q frags straight from global: qf[ih][kh], row i = ih*16+lr
    half8 qf[2][2];
    #pragma unroll
    for (int ih = 0; ih < 2; ih++) {
        const half_t* qsrc = &qs_h[((size_t)(b * 512 + i0 + ih * 16 + lr)) * 1024 + h * 64];
        qf[ih][0] = *(const half8*)(qsrc + quad * 8);
        qf[ih][1] = *(const half8*)(qsrc + 32 + quad * 8);
    }

    floatx4 zero = {0.f, 0.f, 0.f, 0.f};
    // bias GEMM: bt[i][t-64] = q_i . embc[t]; wave -> (ih = jh&1, tk chunk)
    {
        int ih = jh & 1;
        for (int tk = 4 + (jh >> 1); tk < 17; tk += 4) {
            floatx4 acc = zero;
            half8 e0 = *(const half8*)&embc[(size_t)(tk * 16 + lr) * 64 + quad * 8];
            half8 e1 = *(const half8*)&embc[(size_t)(tk * 16 + lr) * 64 + 32 + quad * 8];
            acc = mfma16(e0, qf[ih][0], acc);    // D[m=t][n=i]
            acc = mfma16(e1, qf[ih][1], acc);
            #pragma unroll
            for (int r = 0; r < 4; r++)
                bt[(ih * 16 + lr) * 210 + tk * 16 + quad * 4 + r - 64] = (half_t)acc[r];
        }
    }
    __syncthreads();   // bt ready

    // per-lane constants
    float bfv[2][4];
    #pragma unroll
    for (int ih = 0; ih < 2; ih++)
        #pragma unroll
        for (int r = 0; r < 4; r++) {
            int f = (lr & 7) - ((quad & 1) * 4 + r) + 7;     // 0..14
            bfv[ih][r] = (float)bt[(ih * 16 + lr) * 210 + 192 + f];
        }
    const int qtr0 = (i0 + lr) >> 3;
    const int qtr1 = (i0 + 16 + lr) >> 3;

    floatx4 accO[2][4];
    #pragma unroll
    for (int ih = 0; ih < 2; ih++)
        #pragma unroll
        for (int ni = 0; ni < 4; ni++) accO[ih][ni] = zero;
    floatx4 accS[2];
    accS[0] = zero; accS[1] = zero;
    const half4v vone = {(half_t)1.f, (half_t)1.f, (half_t)1.f, (half_t)1.f};

    // prefetch for jt=0: K (wave's 16 rows x 64 k) and V (4 d-chunks)
    half8 kc0, kc1; half4v vb[4];
    {
        const half_t* kb = &Kc[((size_t)bh * 1536 + jh * 16 + lr) * 64];
        kc0 = *(const half8*)(kb + quad * 8);
        kc1 = *(const half8*)(kb + 32 + quad * 8);
        const half_t* vbase = Vc4 + (size_t)bh * 98304;
        const int jc = jh * 4 + quad;
        #pragma unroll
        for (int ni = 0; ni < 4; ni++)
            vb[ni] = *(const half4v*)&vbase[((size_t)jc * 64 + ni * 16 + lr) * 4];
    }

    for (int jt = 0; jt < 16; ++jt) {
        // prefetch K and V for NEXT iter
        half8 kn0, kn1; half4v vn[4];
        if (jt < 15) {
            const int j1 = (jt + 1) * 128;
            const half_t* kb = (j1 < 1536)
                ? &Kc[((size_t)bh * 1536 + j1 + jh * 16 + lr) * 64]
                : &kp_h[((size_t)(b * 512 + j1 - 1536 + jh * 16 + lr)) * 256 + g * 64];
            kn0 = *(const half8*)(kb + quad * 8);
            kn1 = *(const half8*)(kb + 32 + quad * 8);
            const half_t* vbase; int jcb;
            if (j1 < 1536) { vbase = Vc4 + (size_t)bh * 98304;          jcb = j1 >> 2; }
            else           { vbase = Vp4 + (size_t)(b * 4 + g) * 32768; jcb = (j1 - 1536) >> 2; }
            const int jc = jcb + jh * 4 + quad;
            #pragma unroll
            for (int ni = 0; ni < 4; ni++)
                vn[ni] = *(const half4v*)&vbase[((size_t)jc * 64 + ni * 16 + lr) * 4];
        }

        // S^T = K . Q^T : D[m = j-offset quad*4+r][n = i = ih*16+lr]
        floatx4 s[2];
        #pragma unroll
        for (int ih = 0; ih < 2; ih++) {
            s[ih] = mfma16(kc0, qf[ih][0], zero);
            s[ih] = mfma16(kc1, qf[ih][1], s[ih]);
        }
        // bias + exp2 (no max: scores bounded)
        const int ktb = jt * 16 + jh * 2 + (quad >> 1);
        #pragma unroll
        for (int ih = 0; ih < 2; ih++) {
            int toff = 255 + (ih ? qtr1 : qtr0) - ktb;
            toff = min(toff, 190);
            float tb = (float)bt[(ih * 16 + lr) * 210 + toff];
            #pragma unroll
            for (int r = 0; r < 4; r++)
                s[ih][r] = exp2f(s[ih][r] + tb + bfv[ih][r]);
        }
        // P -> A-frags (m=lane=i, k=quad*4+r=j) ; PV + ones-MFMA row sums
        #pragma unroll
        for (int ih = 0; ih < 2; ih++) {
            half4v pf;
            #pragma unroll
            for (int r = 0; r < 4; r++) pf[r] = (half_t)s[ih][r];
            accS[ih] = mfma16x16(pf, vone, accS[ih]);
            #pragma unroll
            for (int ni = 0; ni < 4; ni++)
                accO[ih][ni] = mfma16x16(pf, vb[ni], accO[ih][ni]);
        }
        if (jt < 15) {
            kc0 = kn0; kc1 = kn1;
            #pragma unroll
            for (int ni = 0; ni < 4; ni++) vb[ni] = vn[ni];
        }
    }

    // 8-way jh merge in LDS (bt dead after this barrier)
    __syncthreads();
    float* Mf = (float*)smem_raw;          // 7 partials x 32 x 68 fp32
    float* Sf = Mf + 7 * 32 * 68;          // 7 x 32 fp32
    if (jh != 0) {
        const int p = jh - 1;
        #pragma unroll
        for (int ih = 0; ih < 2; ih++) {
            #pragma unroll
            for (int ni = 0; ni < 4; ni++)
                #pragma unroll
                for (int r = 0; r < 4; r++)
                    Mf[(p * 32 + ih * 16 + quad * 4 + r) * 68 + ni * 16 + lr] = accO[ih][ni][r];
            if (lr == 0) {
                #pragma unroll
                for (int r = 0; r < 4; r++)
                    Sf[p * 32 + ih * 16 + quad * 4 + r] = accS[ih][r];
            }
        }
    }
    __syncthreads();
    if (jh == 0) {
        #pragma unroll
        for (int ih = 0; ih < 2; ih++) {
            float inv[4];
            #pragma unroll
            for (int r = 0; r < 4; r++) {
                float t = accS[ih][r];
                #pragma unroll
                for (int p = 0; p < 7; p++) t += Sf[p * 32 + ih * 16 + quad * 4 + r];
                inv[r] = 1.0f / t;
            }
            #pragma unroll
            for (int ni = 0; ni < 4; ni++)
                #pragma unroll
                for (int r = 0; r < 4; r++) {
                    float o = accO[ih][ni][r];
                    #pragma unroll
                    for (int p = 0; p < 7; p++)
                        o += Mf[(p * 32 + ih * 16 + quad * 4 + r) * 68 + ni * 16 + lr];
                    int row = ih * 16 + quad * 4 + r;
                    AO[((size_t)(b * 512 + i0 + row)) * 1024 + h * 64 + ni * 16 + lr] =
                        (half_t)(o * inv[r]);
                }
        }
    }
}

// ---------------------------------------------------------------------------
extern "C" void kernel_launch(void* const* d_in, const int* in_sizes, int n_in,
                              void* d_out, int out_size, void* d_ws, size_t ws_size,
                              hipStream_t stream)
{
    const float* q       = (const float*)d_in[0];
    const float* k       = (const float*)d_in[1];
    const float* v       = (const float*)d_in[2];
    const float* cache_k = (const float*)d_in[3];
    const float* cache_v = (const float*)d_in[4];
    const float* Wq      = (const float*)d_in[5];
    const float* Wk      = (const float*)d_in[6];
    const float* Wv      = (const float*)d_in[7];
    const float* Wo      = (const float*)d_in[8];
    const float* emb_t   = (const float*)d_in[9];
    const float* emb_f   = (const float*)d_in[10];

    float* out   = (float*)d_out;                 // (2,512,1024)
    float* out_k = out + 1048576;                 // (32,64,1536)
    float* out_v = out_k + 3145728;               // (32,1536,64)

    half_t* ws = (half_t*)d_ws;
    half_t* qs_h = ws;                  // 1048576
    half_t* kp_h = ws + 1048576;        //  262144
    half_t* Vp4  = ws + 1310720;        //  262144  (2*4 groups)[128][64][4]
    half_t* Kc   = ws + 1572864;        // 3145728
    half_t* Vc4  = ws + 4718592;        // 3145728  [32][384][64][4]
    half_t* WqT  = ws + 7864320;        // 1048576
    half_t* WkvT = ws + 8912896;        //  524288
    half_t* WoT  = ws + 9437184;        // 1048576
    half_t* embc = ws + 10485760;       //   20480
    half_t* AO   = ws + 10506240;       // 1048576

    prepw<<<dim3(720), 256, 0, stream>>>(Wq, Wk, Wv, Wo, emb_t, emb_f,
                                         WqT, WkvT, WoT, embc);
    stage1<<<dim3(1152), 512, 0, stream>>>(q, k, v, cache_k, cache_v,
                                           WqT, WkvT, qs_h, kp_h, Vp4,
                                           Kc, Vc4, out_k, out_v);
    flash<<<dim3(32, 16), 512, 0, stream>>>(qs_h, Kc, kp_h, Vc4, Vp4, embc, AO);
    proj1<<<dim3(256), 512, 0, stream>>>(AO, WoT, out);
}